// Round 1
// baseline (115.580 us; speedup 1.0000x reference)
//
#include <hip/hip_runtime.h>

// ---------------------------------------------------------------------------
// LinearSelfAttention: out = Q@state + tril(Q Q^T, -1) @ V ; new_state = state + Q^T V
// B=4 T=2048 nh=8 N=64 D=128.  Chunked linear-attention decomposition:
//   segment = 128 rows, G=16 segments; per (b,n):
//   phase1:  S_g = Q_seg^T V_seg            (stored transposed [D][N], fp32 ws1)
//   prefix:  P_g = state + sum_{g'<g} S_g'  (bf16 ws2) ; new_state = state + sum S_g
//   phase2:  per 64-chunk c: O = Q_c @ P + tril(Q_c Q_c^T,-1) @ V_c ; P += Q_c^T V_c
// All MFMA = f32_16x16x32_bf16.  C/D layout: col=lane&15, row=quad*4+reg (m89).
// A frag: A[m=lane&15][k=quad*8+j]; B frag: B[k=quad*8+j][n=lane&15].
// ---------------------------------------------------------------------------

using floatx4 = __attribute__((ext_vector_type(4))) float;
using shortx8 = __attribute__((ext_vector_type(8))) short;   // 8 bf16 (4 VGPRs) per guide
using shortx4 = __attribute__((ext_vector_type(4))) short;
using float4v = __attribute__((ext_vector_type(4))) float;

#define MFMA16(a, b, c) __builtin_amdgcn_mfma_f32_16x16x32_bf16((a), (b), (c), 0, 0, 0)

__device__ __forceinline__ unsigned short f2bf(float f) {
  unsigned int u = __builtin_bit_cast(unsigned int, f);
  u += 0x7FFFu + ((u >> 16) & 1u);   // round-to-nearest-even
  return (unsigned short)(u >> 16);
}
__device__ __forceinline__ float bf2f(unsigned short h) {
  unsigned int u = ((unsigned int)h) << 16;
  return __builtin_bit_cast(float, u);
}

// ---------------------------------------------------------------------------
// Phase 1: per (b,n,g) compute St[d][i] = sum_{t in seg} V[t][d] * Q[t][i]
// grid 512, block 256.  ws1 layout: [(b*8+n)*16+g][d*64+i] fp32.
// ---------------------------------------------------------------------------
__global__ __launch_bounds__(256) void k_phase1(const float* __restrict__ Q,
                                                const float* __restrict__ V,
                                                float* __restrict__ ws1) {
  __shared__ unsigned short Qs[128 * 66];   // [t][i], ld 66 (1-bank/row rotation for strided b16)
  __shared__ unsigned short Vs[128 * 130];  // [t][d], ld 130

  const int id = blockIdx.x;
  const int n = id & 7, g = (id >> 3) & 15, b = id >> 7;
  const int t0 = g * 128;
  const int tid = threadIdx.x;

  const float* qbase = Q + (((b * 2048 + t0) * 8 + n) * 64);
  const float* vbase = V + ((b * 2048 + t0) * 128);

#pragma unroll
  for (int it = 0; it < 8; ++it) {          // Q: 128x64 = 2048 float4
    int l = tid + it * 256;
    int t = l >> 4, k4 = (l & 15) * 4;
    float4v q = *(const float4v*)(qbase + t * 512 + k4);
    unsigned int p0 = (unsigned int)f2bf(q.x) | ((unsigned int)f2bf(q.y) << 16);
    unsigned int p1 = (unsigned int)f2bf(q.z) | ((unsigned int)f2bf(q.w) << 16);
    *(unsigned int*)&Qs[t * 66 + k4]     = p0;
    *(unsigned int*)&Qs[t * 66 + k4 + 2] = p1;
  }
#pragma unroll
  for (int it = 0; it < 16; ++it) {         // V: 128x128 = 4096 float4
    int l = tid + it * 256;
    int u = l >> 5, d4 = (l & 31) * 4;
    float4v v = *(const float4v*)(vbase + u * 128 + d4);
    unsigned int p0 = (unsigned int)f2bf(v.x) | ((unsigned int)f2bf(v.y) << 16);
    unsigned int p1 = (unsigned int)f2bf(v.z) | ((unsigned int)f2bf(v.w) << 16);
    *(unsigned int*)&Vs[u * 130 + d4]     = p0;
    *(unsigned int*)&Vs[u * 130 + d4 + 2] = p1;
  }
  __syncthreads();

  const int wave = tid >> 6, lane = tid & 63;
  const int col = lane & 15, quad = lane >> 4;

  // D'[m=d(128)][n=i(64)], wave handles i-tile = wave, all 8 d-tiles. K = 128 (t).
  floatx4 acc[8];
#pragma unroll
  for (int dm = 0; dm < 8; ++dm) acc[dm] = (floatx4){0.f, 0.f, 0.f, 0.f};

#pragma unroll
  for (int s = 0; s < 4; ++s) {
    const int tb = s * 32 + quad * 8;
    shortx8 bq;
    {
      const int i = wave * 16 + col;
#pragma unroll
      for (int j = 0; j < 8; ++j) bq[j] = (short)Qs[(tb + j) * 66 + i];
    }
#pragma unroll
    for (int dm = 0; dm < 8; ++dm) {
      shortx8 av;
      const int d = dm * 16 + col;
#pragma unroll
      for (int j = 0; j < 8; ++j) av[j] = (short)Vs[(tb + j) * 130 + d];
      acc[dm] = MFMA16(av, bq, acc[dm]);
    }
  }

  float* wbase = ws1 + (size_t)((b * 8 + n) * 16 + g) * 8192;
#pragma unroll
  for (int dm = 0; dm < 8; ++dm)
#pragma unroll
    for (int r = 0; r < 4; ++r) {
      int d = dm * 16 + quad * 4 + r;
      int i = wave * 16 + col;
      wbase[d * 64 + i] = acc[dm][r];
    }
}

// ---------------------------------------------------------------------------
// Prefix over segments.  grid 1024, block 256 (one thread per (bn, d, i)).
// ws2[(bn*16+g)][d*64+i] = bf16( state + sum_{g'<g} S_g' ) ; new_state written fp32.
// ---------------------------------------------------------------------------
__global__ __launch_bounds__(256) void k_prefix(const float* __restrict__ state,
                                                const float* __restrict__ ws1,
                                                unsigned short* __restrict__ ws2,
                                                float* __restrict__ new_state) {
  int tid = blockIdx.x * 256 + threadIdx.x;  // 0 .. 262143
  int bn = tid >> 13;
  int e = tid & 8191;
  int d = e >> 6, i = e & 63;
  float run = state[(bn * 64 + i) * 128 + d];
  const float* w1 = ws1 + (size_t)bn * 16 * 8192 + e;
  unsigned short* w2 = ws2 + (size_t)bn * 16 * 8192 + e;
#pragma unroll
  for (int g = 0; g < 16; ++g) {
    w2[g * 8192] = f2bf(run);
    run += w1[g * 8192];
  }
  new_state[(bn * 64 + i) * 128 + d] = run;
}

// ---------------------------------------------------------------------------
// Phase 2: per (b,n,g): two 64-chunks.
//   O_c = Q_c @ P  +  tril(Q_c Q_c^T, -1) @ V_c ;  after c=0: P += Q_0^T V_0.
// grid 512, block 256.  LDS 52.2 KB -> 3 blocks/CU.
// ---------------------------------------------------------------------------
__global__ __launch_bounds__(256) void k_phase2(const float* __restrict__ Q,
                                                const float* __restrict__ V,
                                                const unsigned short* __restrict__ ws2,
                                                float* __restrict__ out) {
  __shared__ unsigned short Qs[64 * 72];    // [t][k]  ld 72 (16B-aligned rows, 4-bank rotation)
  __shared__ unsigned short Vs[64 * 130];   // [u][d]  ld 130 (strided b16 reads conflict-free)
  __shared__ unsigned short Ss[64 * 72];    // [t][u]  masked scores
  __shared__ unsigned short Pt[128 * 72];   // [d][i]  running state transposed

  const int id = blockIdx.x;
  const int n = id & 7, g = (id >> 3) & 15, b = id >> 7;
  const int t0 = g * 128;
  const int tid = threadIdx.x;
  const int wave = tid >> 6, lane = tid & 63;
  const int col = lane & 15, quad = lane >> 4;

  // stage Pt (bf16 straight copy, linear)
  {
    const unsigned short* pb = ws2 + (size_t)((b * 8 + n) * 16 + g) * 8192;
#pragma unroll
    for (int it = 0; it < 8; ++it) {
      int l = tid + it * 256;               // 0..2047 ; e = l*4
      int d = l >> 4, i4 = (l & 15) * 4;
      shortx4 v = *(const shortx4*)(pb + l * 4);
      *(shortx4*)&Pt[d * 72 + i4] = v;
    }
  }

  const float* qbase = Q + (((b * 2048 + t0) * 8 + n) * 64);
  const float* vbase = V + ((b * 2048 + t0) * 128);
  float* obase = out + (((b * 2048 + t0) * 8 + n) * 128);

  for (int c = 0; c < 2; ++c) {
    // ---- stage chunk Q (64x64) and V (64x128) ----
#pragma unroll
    for (int it = 0; it < 4; ++it) {
      int l = tid + it * 256;
      int t = l >> 4, k4 = (l & 15) * 4;
      float4v q = *(const float4v*)(qbase + (c * 64 + t) * 512 + k4);
      unsigned int p0 = (unsigned int)f2bf(q.x) | ((unsigned int)f2bf(q.y) << 16);
      unsigned int p1 = (unsigned int)f2bf(q.z) | ((unsigned int)f2bf(q.w) << 16);
      *(unsigned int*)&Qs[t * 72 + k4]     = p0;
      *(unsigned int*)&Qs[t * 72 + k4 + 2] = p1;
    }
#pragma unroll
    for (int it = 0; it < 8; ++it) {
      int l = tid + it * 256;
      int u = l >> 5, d4 = (l & 31) * 4;
      float4v v = *(const float4v*)(vbase + (c * 64 + u) * 128 + d4);
      unsigned int p0 = (unsigned int)f2bf(v.x) | ((unsigned int)f2bf(v.y) << 16);
      unsigned int p1 = (unsigned int)f2bf(v.z) | ((unsigned int)f2bf(v.w) << 16);
      *(unsigned int*)&Vs[u * 130 + d4]     = p0;
      *(unsigned int*)&Vs[u * 130 + d4 + 2] = p1;
    }
    __syncthreads();   // B1: staging (and Pt / Pt-update) visible

    // ---- scores: S[t][u] = sum_k Q[t][k]Q[u][k], strict-causal mask, -> Ss ----
    {
      int job = 0;
      for (int ti = 0; ti < 4; ++ti)
        for (int ui = 0; ui <= (ti | 1); ++ui, ++job) {
          if ((job & 3) != wave) continue;
          if (ui > ti) {                    // fully-masked tile touched by k-loop: zero it
#pragma unroll
            for (int r = 0; r < 4; ++r)
              Ss[(ti * 16 + quad * 4 + r) * 72 + ui * 16 + col] = 0;
          } else {
            floatx4 sc = (floatx4){0.f, 0.f, 0.f, 0.f};
#pragma unroll
            for (int s = 0; s < 2; ++s) {
              shortx8 at = *(const shortx8*)&Qs[(ti * 16 + col) * 72 + s * 32 + quad * 8];
              shortx8 au = *(const shortx8*)&Qs[(ui * 16 + col) * 72 + s * 32 + quad * 8];
              sc = MFMA16(at, au, sc);
            }
#pragma unroll
            for (int r = 0; r < 4; ++r) {
              int t = ti * 16 + quad * 4 + r, u = ui * 16 + col;
              Ss[t * 72 + u] = (u < t) ? f2bf(sc[r]) : (unsigned short)0;
            }
          }
        }
    }
    __syncthreads();   // B2: Ss visible

    // ---- output accum: wave handles d-tiles {2w, 2w+1}, all 4 t-tiles ----
    floatx4 acc[4][2];
#pragma unroll
    for (int ti = 0; ti < 4; ++ti)
#pragma unroll
      for (int dj = 0; dj < 2; ++dj) acc[ti][dj] = (floatx4){0.f, 0.f, 0.f, 0.f};

    // Q @ P   (K = 64 over i)
#pragma unroll
    for (int s = 0; s < 2; ++s) {
      shortx8 bp[2];
#pragma unroll
      for (int dj = 0; dj < 2; ++dj)
        bp[dj] = *(const shortx8*)&Pt[((wave * 2 + dj) * 16 + col) * 72 + s * 32 + quad * 8];
#pragma unroll
      for (int ti = 0; ti < 4; ++ti) {
        shortx8 aq = *(const shortx8*)&Qs[(ti * 16 + col) * 72 + s * 32 + quad * 8];
#pragma unroll
        for (int dj = 0; dj < 2; ++dj) acc[ti][dj] = MFMA16(aq, bp[dj], acc[ti][dj]);
      }
    }
    // scores @ V  (K up to 64 over u; skip all-zero upper k-steps)
#pragma unroll
    for (int s = 0; s < 2; ++s) {
      shortx8 bv[2];
#pragma unroll
      for (int dj = 0; dj < 2; ++dj) {
        int d = (wave * 2 + dj) * 16 + col;
        int ub = s * 32 + quad * 8;
#pragma unroll
        for (int j = 0; j < 8; ++j) bv[dj][j] = (short)Vs[(ub + j) * 130 + d];
      }
      for (int ti = (s == 0 ? 0 : 2); ti < 4; ++ti) {
        shortx8 as = *(const shortx8*)&Ss[(ti * 16 + col) * 72 + s * 32 + quad * 8];
#pragma unroll
        for (int dj = 0; dj < 2; ++dj) acc[ti][dj] = MFMA16(as, bv[dj], acc[ti][dj]);
      }
    }
    // store O chunk
#pragma unroll
    for (int ti = 0; ti < 4; ++ti)
#pragma unroll
      for (int dj = 0; dj < 2; ++dj)
#pragma unroll
        for (int r = 0; r < 4; ++r) {
          int t = c * 64 + ti * 16 + quad * 4 + r;
          int d = (wave * 2 + dj) * 16 + col;
          obase[t * 1024 + d] = acc[ti][dj][r];
        }

    if (c == 0) {
      // ---- P += Q_0^T V_0 : U[d][i], wave handles i-tile = wave, 8 d-tiles ----
      floatx4 ua[8];
#pragma unroll
      for (int dm = 0; dm < 8; ++dm) ua[dm] = (floatx4){0.f, 0.f, 0.f, 0.f};
#pragma unroll
      for (int s = 0; s < 2; ++s) {
        const int tb = s * 32 + quad * 8;
        shortx8 bq;
        {
          const int i = wave * 16 + col;
#pragma unroll
          for (int j = 0; j < 8; ++j) bq[j] = (short)Qs[(tb + j) * 72 + i];
        }
#pragma unroll
        for (int dm = 0; dm < 8; ++dm) {
          shortx8 av;
          const int d = dm * 16 + col;
#pragma unroll
          for (int j = 0; j < 8; ++j) av[j] = (short)Vs[(tb + j) * 130 + d];
          ua[dm] = MFMA16(av, bq, ua[dm]);
        }
      }
      __syncthreads();  // B3: everyone done READING Pt before we overwrite it
#pragma unroll
      for (int dm = 0; dm < 8; ++dm)
#pragma unroll
        for (int r = 0; r < 4; ++r) {
          int d = dm * 16 + quad * 4 + r;
          int i = wave * 16 + col;
          int idx = d * 72 + i;
          Pt[idx] = f2bf(bf2f(Pt[idx]) + ua[dm][r]);
        }
      __syncthreads();  // B4: Pt update visible; Qs/Vs free for restage
    }
  }
}

// ---------------------------------------------------------------------------
extern "C" void kernel_launch(void* const* d_in, const int* in_sizes, int n_in,
                              void* d_out, int out_size, void* d_ws, size_t ws_size,
                              hipStream_t stream) {
  (void)in_sizes; (void)n_in; (void)out_size; (void)ws_size;
  const float* Q     = (const float*)d_in[0];
  const float* V     = (const float*)d_in[1];
  const float* state = (const float*)d_in[2];
  float* out        = (float*)d_out;
  float* new_state  = out + (size_t)4 * 2048 * 8 * 128;     // after output tensor
  float* ws1        = (float*)d_ws;                          // 512 * 8192 fp32 = 16.8 MB
  unsigned short* ws2 = (unsigned short*)((char*)d_ws + (size_t)512 * 8192 * 4);  // 8.4 MB bf16

  k_phase1<<<512, 256, 0, stream>>>(Q, V, ws1);
  k_prefix<<<1024, 256, 0, stream>>>(state, ws1, ws2, new_state);
  k_phase2<<<512, 256, 0, stream>>>(Q, V, ws2, out);
}

// Round 2
// 101.342 us; speedup vs baseline: 1.1405x; 1.1405x over previous
//
#include <hip/hip_runtime.h>

// ---------------------------------------------------------------------------
// LinearSelfAttention: out = Q@state + tril(Q Q^T,-1)@V ; new_state = state + Q^T V
// B=4 T=2048 nh=8 N=64 D=128.  3-dispatch chunked decomposition, segment=128:
//   phase1:  S_g[i][d] = sum_{t in seg} Q[t][i] V[t][d]   (fp32 ws1, [i][d])
//   prefix:  P_g = state + sum_{g'<g} S_g'  (bf16 ws2, [i][d]); new_state fp32
//   phase2:  per 64-chunk c: O = Q_c@P + tril(Q_c Q_c^T,-1)@V_c ; P += Q_c^T V_c
// All MFMA = f32_16x16x32_bf16.  C/D: col=lane&15, row=quad*4+reg (m89-verified).
// A frag: A[m=lane&15][k=quad*8+j]; B frag: B[k=quad*8+j][n=lane&15].
// R2 changes vs R1: all fragments via vector LDS reads (B-operands staged
// TRANSPOSED with convert-transpose staging), [i][d] ws layout (prefix fully
// coalesced), XCD swizzle (n in high block-id bits -> V shared in XCD L2).
// ---------------------------------------------------------------------------

using floatx4 = __attribute__((ext_vector_type(4))) float;
using float4v = __attribute__((ext_vector_type(4))) float;
using shortx8 = __attribute__((ext_vector_type(8))) short;
using shortx4 = __attribute__((ext_vector_type(4))) short;
using uint2v  = __attribute__((ext_vector_type(2))) unsigned int;

#define MFMA16(a, b, c) __builtin_amdgcn_mfma_f32_16x16x32_bf16((a), (b), (c), 0, 0, 0)

__device__ __forceinline__ unsigned short f2bf(float f) {
  unsigned int u = __builtin_bit_cast(unsigned int, f);
  u += 0x7FFFu + ((u >> 16) & 1u);   // RNE
  return (unsigned short)(u >> 16);
}
__device__ __forceinline__ float bf2f(unsigned short h) {
  unsigned int u = ((unsigned int)h) << 16;
  return __builtin_bit_cast(float, u);
}
__device__ __forceinline__ unsigned int pack2(float a, float b) {
  return (unsigned int)f2bf(a) | ((unsigned int)f2bf(b) << 16);
}
// 8 consecutive bf16 from LDS, 8B-aligned (2x ds_read_b64)
__device__ __forceinline__ shortx8 lds8(const unsigned short* p) {
  shortx4 a = *(const shortx4*)p;
  shortx4 b = *(const shortx4*)(p + 4);
  return __builtin_shufflevector(a, b, 0, 1, 2, 3, 4, 5, 6, 7);
}

// ---------------------------------------------------------------------------
// Phase 1: S_g[i][d] = sum_t Q[t][i] V[t][d].  grid 512, block 256.
// Qt[i][t], Vt[d][t], ld=132 shorts (66 u32, odd-ish stride: 4-way write
// conflicts max, b64 reads 2-way max).  D[m=i][n=d]: A=Qt rows, B=Vt rows.
// ---------------------------------------------------------------------------
__global__ __launch_bounds__(256) void k_phase1(const float* __restrict__ Q,
                                                const float* __restrict__ V,
                                                float* __restrict__ ws1) {
  __shared__ unsigned short Qt[64 * 132];   // [i][t]
  __shared__ unsigned short Vt[128 * 132];  // [d][t]

  const int id = blockIdx.x;
  const int n = id >> 6, bg = id & 63, b = bg >> 4, g = bg & 15;  // XCD swizzle
  const int t0 = g * 128;
  const int tid = threadIdx.x;

  const float* qbase = Q + (((size_t)(b * 2048 + t0) * 8 + n) * 64);
  const float* vbase = V + ((size_t)(b * 2048 + t0) * 128);

  // convert-transpose staging: coalesced dword loads, paired-t u32 LDS writes
#pragma unroll 8
  for (int it = 0; it < 16; ++it) {         // Q: 64i x 64 t-pairs
    int j = tid + it * 256;
    int i = j & 63, p = j >> 6;
    float q0 = qbase[(2 * p) * 512 + i];
    float q1 = qbase[(2 * p + 1) * 512 + i];
    *(unsigned int*)&Qt[i * 132 + 2 * p] = pack2(q0, q1);
  }
#pragma unroll 8
  for (int it = 0; it < 32; ++it) {         // V: 128d x 64 t-pairs
    int j = tid + it * 256;
    int d = j & 127, p = j >> 7;
    float v0 = vbase[(2 * p) * 128 + d];
    float v1 = vbase[(2 * p + 1) * 128 + d];
    *(unsigned int*)&Vt[d * 132 + 2 * p] = pack2(v0, v1);
  }
  __syncthreads();

  const int wave = tid >> 6, lane = tid & 63;
  const int col = lane & 15, quad = lane >> 4;

  // wave -> d-tiles {2w,2w+1}, all 4 i-tiles.  K = 128 over t.
  floatx4 acc[4][2];
#pragma unroll
  for (int ti = 0; ti < 4; ++ti)
#pragma unroll
    for (int dj = 0; dj < 2; ++dj) acc[ti][dj] = (floatx4){0.f, 0.f, 0.f, 0.f};

#pragma unroll
  for (int s = 0; s < 4; ++s) {
    const int koff = s * 32 + quad * 8;
    shortx8 bv[2];
#pragma unroll
    for (int dj = 0; dj < 2; ++dj)
      bv[dj] = lds8(&Vt[((wave * 2 + dj) * 16 + col) * 132 + koff]);
#pragma unroll
    for (int ti = 0; ti < 4; ++ti) {
      shortx8 aq = lds8(&Qt[(ti * 16 + col) * 132 + koff]);
#pragma unroll
      for (int dj = 0; dj < 2; ++dj) acc[ti][dj] = MFMA16(aq, bv[dj], acc[ti][dj]);
    }
  }

  float* wbase = ws1 + (size_t)((b * 8 + n) * 16 + g) * 8192;
#pragma unroll
  for (int ti = 0; ti < 4; ++ti)
#pragma unroll
    for (int dj = 0; dj < 2; ++dj)
#pragma unroll
      for (int r = 0; r < 4; ++r) {
        int i = ti * 16 + quad * 4 + r;
        int d = (wave * 2 + dj) * 16 + col;
        wbase[i * 128 + d] = acc[ti][dj][r];
      }
}

// ---------------------------------------------------------------------------
// Prefix over 16 segments, [i][d] layout: ALL accesses coalesced.
// grid 1024, block 256.
// ---------------------------------------------------------------------------
__global__ __launch_bounds__(256) void k_prefix(const float* __restrict__ state,
                                                const float* __restrict__ ws1,
                                                unsigned short* __restrict__ ws2,
                                                float* __restrict__ new_state) {
  int t = blockIdx.x * 256 + threadIdx.x;   // 0 .. 262143
  int bn = t >> 13;
  int e = t & 8191;                          // e = i*128 + d
  float run = state[bn * 8192 + e];
  const float* w1 = ws1 + (size_t)bn * 131072 + e;
  unsigned short* w2 = ws2 + (size_t)bn * 131072 + e;
#pragma unroll
  for (int g = 0; g < 16; ++g) {
    w2[g * 8192] = f2bf(run);
    run += w1[g * 8192];
  }
  new_state[bn * 8192 + e] = run;
}

// ---------------------------------------------------------------------------
// Phase 2: per (b,n,g): two 64-chunks.
//   O_c = Q_c @ P + tril(Q_c Q_c^T,-1) @ V_c ; after c=0: P += Q_0^T V_0.
// LDS 53.2 KB -> 3 blocks/CU.  Vt/Pt ld=68 (34 u32), Qs/Ss ld=72 (b128 rows).
// ---------------------------------------------------------------------------
__global__ __launch_bounds__(256) void k_phase2(const float* __restrict__ Q,
                                                const float* __restrict__ V,
                                                const unsigned short* __restrict__ ws2,
                                                float* __restrict__ out) {
  __shared__ unsigned short Qs[64 * 72];    // [t][k]  A-rows b128; update-B scalar cols
  __shared__ unsigned short Vt[128 * 68];   // [d][u]  B/A rows b64x2
  __shared__ unsigned short Ss[64 * 72];    // [t][u]  masked scores, A-rows b128
  __shared__ unsigned short Pt[128 * 68];   // [d][i]  running state, B rows b64x2

  const int id = blockIdx.x;
  const int n = id >> 6, bg = id & 63, b = bg >> 4, g = bg & 15;  // XCD swizzle
  const int t0 = g * 128;
  const int tid = threadIdx.x;
  const int wave = tid >> 6, lane = tid & 63;
  const int col = lane & 15, quad = lane >> 4;

  // stage Pt: transpose ws2 [i][d] -> Pt[d][i]
  {
    const unsigned int* pb32 =
        (const unsigned int*)(ws2 + (size_t)((b * 8 + n) * 16 + g) * 8192);
#pragma unroll 8
    for (int it = 0; it < 16; ++it) {
      int j = tid + it * 256;
      int d2 = j & 63, i = j >> 6;
      unsigned int u = pb32[i * 64 + d2];   // coalesced: d2 fastest
      Pt[(2 * d2) * 68 + i] = (unsigned short)(u & 0xFFFFu);
      Pt[(2 * d2 + 1) * 68 + i] = (unsigned short)(u >> 16);
    }
  }

  const float* qbase = Q + (((size_t)(b * 2048 + t0) * 8 + n) * 64);
  const float* vbase = V + ((size_t)(b * 2048 + t0) * 128);
  float* obase = out + (((size_t)(b * 2048 + t0) * 8 + n) * 128);

  for (int c = 0; c < 2; ++c) {
    // ---- stage Qs [t][k] (b64 writes) and Vt [d][u] (convert-transpose) ----
#pragma unroll
    for (int it = 0; it < 4; ++it) {
      int l = tid + it * 256;
      int t = l >> 4, k4 = (l & 15) * 4;
      float4v q = *(const float4v*)(qbase + (size_t)(c * 64 + t) * 512 + k4);
      uint2v u;
      u.x = pack2(q.x, q.y);
      u.y = pack2(q.z, q.w);
      *(uint2v*)&Qs[t * 72 + k4] = u;
    }
#pragma unroll 8
    for (int it = 0; it < 16; ++it) {
      int j = tid + it * 256;
      int d = j & 127, p = j >> 7;          // u = 2p, 2p+1
      float v0 = vbase[(size_t)(c * 64 + 2 * p) * 128 + d];
      float v1 = vbase[(size_t)(c * 64 + 2 * p + 1) * 128 + d];
      *(unsigned int*)&Vt[d * 68 + 2 * p] = pack2(v0, v1);
    }
    __syncthreads();   // B1

    // ---- scores: S[t][u] = Q Q^T, strict-causal mask -> Ss ----
    {
      int job = 0;
      for (int ti = 0; ti < 4; ++ti)
        for (int ui = 0; ui <= (ti | 1); ++ui, ++job) {
          if ((job & 3) != wave) continue;
          if (ui > ti) {                    // masked tile read by K-loop: zero
#pragma unroll
            for (int r = 0; r < 4; ++r)
              Ss[(ti * 16 + quad * 4 + r) * 72 + ui * 16 + col] = 0;
          } else {
            floatx4 sc = (floatx4){0.f, 0.f, 0.f, 0.f};
#pragma unroll
            for (int s = 0; s < 2; ++s) {
              shortx8 at = *(const shortx8*)&Qs[(ti * 16 + col) * 72 + s * 32 + quad * 8];
              shortx8 au = *(const shortx8*)&Qs[(ui * 16 + col) * 72 + s * 32 + quad * 8];
              sc = MFMA16(at, au, sc);
            }
#pragma unroll
            for (int r = 0; r < 4; ++r) {
              int t = ti * 16 + quad * 4 + r, u = ui * 16 + col;
              Ss[t * 72 + u] = (u < t) ? f2bf(sc[r]) : (unsigned short)0;
            }
          }
        }
    }
    __syncthreads();   // B2

    // ---- O accum: wave -> d-tiles {2w,2w+1}, all 4 t-tiles ----
    floatx4 acc[4][2];
#pragma unroll
    for (int ti = 0; ti < 4; ++ti)
#pragma unroll
      for (int dj = 0; dj < 2; ++dj) acc[ti][dj] = (floatx4){0.f, 0.f, 0.f, 0.f};

    // Q @ P (K=64 over i)
#pragma unroll
    for (int s = 0; s < 2; ++s) {
      const int koff = s * 32 + quad * 8;
      shortx8 bp[2];
#pragma unroll
      for (int dj = 0; dj < 2; ++dj)
        bp[dj] = lds8(&Pt[((wave * 2 + dj) * 16 + col) * 68 + koff]);
#pragma unroll
      for (int ti = 0; ti < 4; ++ti) {
        shortx8 aq = *(const shortx8*)&Qs[(ti * 16 + col) * 72 + koff];
#pragma unroll
        for (int dj = 0; dj < 2; ++dj) acc[ti][dj] = MFMA16(aq, bp[dj], acc[ti][dj]);
      }
    }
    // S @ V (skip all-zero upper K-steps)
#pragma unroll
    for (int s = 0; s < 2; ++s) {
      const int koff = s * 32 + quad * 8;
      shortx8 bv[2];
#pragma unroll
      for (int dj = 0; dj < 2; ++dj)
        bv[dj] = lds8(&Vt[((wave * 2 + dj) * 16 + col) * 68 + koff]);
      for (int ti = (s == 0 ? 0 : 2); ti < 4; ++ti) {
        shortx8 as = *(const shortx8*)&Ss[(ti * 16 + col) * 72 + koff];
#pragma unroll
        for (int dj = 0; dj < 2; ++dj) acc[ti][dj] = MFMA16(as, bv[dj], acc[ti][dj]);
      }
    }
    // store O chunk
#pragma unroll
    for (int ti = 0; ti < 4; ++ti)
#pragma unroll
      for (int dj = 0; dj < 2; ++dj)
#pragma unroll
        for (int r = 0; r < 4; ++r) {
          int t = c * 64 + ti * 16 + quad * 4 + r;
          int d = (wave * 2 + dj) * 16 + col;
          obase[(size_t)t * 1024 + d] = acc[ti][dj][r];
        }

    if (c == 0) {
      // ---- P += Q_0^T V_0 : U[d][i]; wave -> i-tile = wave, 8 d-tiles ----
      floatx4 ua[8];
#pragma unroll
      for (int dm = 0; dm < 8; ++dm) ua[dm] = (floatx4){0.f, 0.f, 0.f, 0.f};
#pragma unroll
      for (int s = 0; s < 2; ++s) {
        const int koff = s * 32 + quad * 8;
        shortx8 bq;                          // B[k=t][n=i] = Qs column (16 reads total)
#pragma unroll
        for (int jj = 0; jj < 8; ++jj)
          bq[jj] = (short)Qs[(koff + jj) * 72 + wave * 16 + col];
#pragma unroll
        for (int dm = 0; dm < 8; ++dm) {
          shortx8 av = lds8(&Vt[(dm * 16 + col) * 68 + koff]);
          ua[dm] = MFMA16(av, bq, ua[dm]);
        }
      }
      __syncthreads();  // B3: all Pt reads done before overwrite
#pragma unroll
      for (int dm = 0; dm < 8; ++dm)
#pragma unroll
        for (int r = 0; r < 4; ++r) {
          int d = dm * 16 + quad * 4 + r;
          int i = wave * 16 + col;
          int idx = d * 68 + i;
          Pt[idx] = f2bf(bf2f(Pt[idx]) + ua[dm][r]);
        }
      __syncthreads();  // B4: Pt update visible; Qs/Vt free for restage
    }
  }
}

// ---------------------------------------------------------------------------
extern "C" void kernel_launch(void* const* d_in, const int* in_sizes, int n_in,
                              void* d_out, int out_size, void* d_ws, size_t ws_size,
                              hipStream_t stream) {
  (void)in_sizes; (void)n_in; (void)out_size; (void)ws_size;
  const float* Q     = (const float*)d_in[0];
  const float* V     = (const float*)d_in[1];
  const float* state = (const float*)d_in[2];
  float* out        = (float*)d_out;
  float* new_state  = out + (size_t)4 * 2048 * 8 * 128;
  float* ws1        = (float*)d_ws;                                       // 16.8 MB fp32 [i][d]
  unsigned short* ws2 = (unsigned short*)((char*)d_ws + (size_t)512 * 8192 * 4);  // 8.4 MB bf16

  k_phase1<<<512, 256, 0, stream>>>(Q, V, ws1);
  k_prefix<<<1024, 256, 0, stream>>>(state, ws1, ws2, new_state);
  k_phase2<<<512, 256, 0, stream>>>(Q, V, ws2, out);
}